// Round 15
// baseline (66.448 us; speedup 1.0000x reference)
//
#include <hip/hip_runtime.h>
#include <math.h>

#define NPIX 1048576
#define HH 64
#define NO 3
#define NBLK 2048
#define ITER 8     // NBLK * 4 waves * ITER * 16 px = 1048576
#define NOUT4 786432             // NPIX*NO/4 float4s
#define K2C 2.8853900817779268f  // 2*log2(e)

typedef float f32x4 __attribute__((ext_vector_type(4)));
typedef __bf16 bf16x8 __attribute__((ext_vector_type(8)));
typedef __bf16 bf16x2 __attribute__((ext_vector_type(2)));

union BF8 { __bf16 h[8]; bf16x8 v; uint4 u4; };
union PK2 { bf16x2 h; unsigned u; };
union F4U { float f[4]; uint4 u; f32x4 v; };

#define MFMA16(a, b, c) __builtin_amdgcn_mfma_f32_16x16x32_bf16((a), (b), (c), 0, 0, 0)

// k-slot -> physical h index permutation: lane (G,q) holds C rows {16m+4G+r}
// and owns B-frag k-slots {8G+j} (Bf0) and {32+8G+j} (Bf1). Bijection:
__device__ __forceinline__ int hsel(int k) {
    const int G = (k & 31) >> 3, j = k & 7;
    return ((k >= 32) ? 32 : 0) + ((j >= 4) ? 16 : 0) + 4 * G + (j & 3);
}

// sigmoid-reciprocal pack (minimum issue count): r = 1/(exp2(t)+1), t pre-scaled
// by 2*log2e with bias folded upstream. tanh(x) = 1 - 2r is ABSORBED INTO THE
// NEXT LAYER: W' = -2W, bias' = bias + W.1 (colsums folded at build).
// 6 VALU + 8 trans per 4 values. Overflow-safe: exp2->inf => rcp->0 => h=1.
__device__ __forceinline__ void rcp4_pack(const f32x4 c, unsigned* lo, unsigned* hi) {
    const float r0 = __builtin_amdgcn_rcpf(__builtin_amdgcn_exp2f(c[0]) + 1.0f);
    const float r1 = __builtin_amdgcn_rcpf(__builtin_amdgcn_exp2f(c[1]) + 1.0f);
    const float r2 = __builtin_amdgcn_rcpf(__builtin_amdgcn_exp2f(c[2]) + 1.0f);
    const float r3 = __builtin_amdgcn_rcpf(__builtin_amdgcn_exp2f(c[3]) + 1.0f);
    PK2 L, H;
    L.h = bf16x2{(__bf16)r0, (__bf16)r1};
    H.h = bf16x2{(__bf16)r2, (__bf16)r3};
    *lo = L.u; *hi = H.u;
}

// pack fused into main: each block rebuilds fragments at entry (W reads are
// L1/L2-hit after block 0; colsums cooperative fp32 — identical math to the
// old 1-block pack kernel, whose dispatch + launch gap this removes).
__global__ __launch_bounds__(256) void cppn_main(
    const float* __restrict__ x,
    const float* __restrict__ W1, const float* __restrict__ b1,
    const float* __restrict__ W2, const float* __restrict__ b2,
    const float* __restrict__ W3, const float* __restrict__ b3,
    float* __restrict__ out,
    float* __restrict__ pmin, float* __restrict__ pmax)
{
    __shared__ float cs2p[4][HH];  // partial column sums of W2 (fp32 exact)
    __shared__ float cs3p[4][NO];  // partial column sums of W3
    __shared__ float rmin[4], rmax[4];

    const int t = threadIdx.x;
    const int w = t >> 6;
    const int l = t & 63;
    const int g = l >> 4;
    const int q = l & 15;

    const int pbase = ((blockIdx.x * 4 + w) * ITER) * 16 + q;  // pixel index, it steps +16
    const float4* x4 = reinterpret_cast<const float4*>(x);
    float4 cur = x4[pbase];  // issue first x load early: HBM latency hides under build

    // ---- cooperative column sums (thread t sums 16 rows of column t&63) ----
    {
        const int col = t & 63, part = t >> 6;
        float s = 0.0f;
        #pragma unroll
        for (int r = 0; r < 16; ++r) s += W2[(part * 16 + r) * HH + col];
        cs2p[part][col] = s;
    }
    if (t < 12) {
        const int o3 = t % 3, part = t / 3;
        float s = 0.0f;
        #pragma unroll
        for (int r = 0; r < 16; ++r) s += W3[(part * 16 + r) * NO + o3];
        cs3p[part][o3] = s;
    }
    __syncthreads();

    // ---- per-lane fragment build, straight into registers ----
    bf16x8 A1[4], A2[2][4], A3[2];
    // L1: A[row=h][k] = K2 * W1aug[k][h]; k<4 -> W1, k==4 -> b1 (bias fold)
    #pragma unroll
    for (int m = 0; m < 4; ++m) {
        BF8 tt;
        #pragma unroll
        for (int j = 0; j < 8; ++j) {
            const int k = g * 8 + j;
            float v = 0.0f;
            if (k < 4) v = W1[k * HH + m * 16 + q];
            else if (k == 4) v = b1[m * 16 + q];
            tt.h[j] = (__bf16)(K2C * v);
        }
        A1[m] = tt.v;
    }
    // L2: A'[row=h2][k] = -2*K2 * W2[hsel(k)][h2]  (consumes r, not h)
    #pragma unroll
    for (int s = 0; s < 2; ++s)
        #pragma unroll
        for (int m = 0; m < 4; ++m) {
            BF8 tt;
            #pragma unroll
            for (int j = 0; j < 8; ++j)
                tt.h[j] = (__bf16)(-2.0f * K2C * W2[hsel(s * 32 + g * 8 + j) * HH + m * 16 + q]);
            A2[s][m] = tt.v;
        }
    // L3: A'[row=o][k] = -2 * W3[hsel(k)][o], rows 3..15 zero
    #pragma unroll
    for (int s = 0; s < 2; ++s) {
        BF8 tt;
        #pragma unroll
        for (int j = 0; j < 8; ++j)
            tt.h[j] = (q < NO) ? (__bf16)(-2.0f * W3[hsel(s * 32 + g * 8 + j) * NO + q])
                               : (__bf16)0.0f;
        A3[s] = tt.v;
    }
    // Ci2' = K2 * (b2 + colsum(W2)) at C rows m*16 + g*4 + r
    f32x4 Ci2[4];
    #pragma unroll
    for (int m = 0; m < 4; ++m) {
        F4U tt;
        #pragma unroll
        for (int r = 0; r < 4; ++r) {
            const int idx = m * 16 + g * 4 + r;
            const float cs = cs2p[0][idx] + cs2p[1][idx] + cs2p[2][idx] + cs2p[3][idx];
            tt.f[r] = K2C * (b2[idx] + cs);
        }
        Ci2[m] = tt.v;
    }
    // Ci3' = b3 + colsum(W3), live on g==0 lanes (C rows 0..2)
    f32x4 Ci3 = {0.0f, 0.0f, 0.0f, 0.0f};
    if (g == 0) {
        #pragma unroll
        for (int c = 0; c < 3; ++c)
            Ci3[c] = b3[c] + cs3p[0][c] + cs3p[1][c] + cs3p[2][c] + cs3p[3][c];
    }

    const f32x4 z = {0.0f, 0.0f, 0.0f, 0.0f};
    float vmin = INFINITY, vmax = -INFINITY;

    #pragma unroll 2
    for (int it = 0; it < ITER; ++it) {
        // prefetch next iteration's x before the long compute body
        const int itn = (it + 1 < ITER) ? it + 1 : it;
        const float4 nxt = x4[pbase + itn * 16];

        // B1 frag: xaug^T[k][px]; only g==0 lanes carry {x0..x3, 1}
        BF8 bx;
        bx.u4 = uint4{0, 0, 0, 0};
        if (g == 0) {
            PK2 p01, p23;
            p01.h = bf16x2{(__bf16)cur.x, (__bf16)cur.y};
            p23.h = bf16x2{(__bf16)cur.z, (__bf16)cur.w};
            bx.u4.x = p01.u;
            bx.u4.y = p23.u;
            bx.u4.z = 0x3F80u;  // {1.0bf16, 0} bias lane k=4
        }

        // ---- layer 1 (A1 pre-scaled by K2, bias k-augmented) ----
        f32x4 c1[4];
        #pragma unroll
        for (int m = 0; m < 4; ++m) c1[m] = MFMA16(A1[m], bx.v, z);

        unsigned pkx[4], pky[4];
        #pragma unroll
        for (int m = 0; m < 4; ++m) rcp4_pack(c1[m], &pkx[m], &pky[m]);
        BF8 Bf0, Bf1;
        Bf0.u4 = uint4{pkx[0], pky[0], pkx[1], pky[1]};
        Bf1.u4 = uint4{pkx[2], pky[2], pkx[3], pky[3]};

        // ---- layer 2 (A2' = -2*K2*W2 consumes r1; bias' via C-init) ----
        f32x4 c2[4];
        #pragma unroll
        for (int m = 0; m < 4; ++m) {
            c2[m] = MFMA16(A2[0][m], Bf0.v, Ci2[m]);
            c2[m] = MFMA16(A2[1][m], Bf1.v, c2[m]);
        }
        #pragma unroll
        for (int m = 0; m < 4; ++m) rcp4_pack(c2[m], &pkx[m], &pky[m]);
        BF8 Bg0, Bg1;
        Bg0.u4 = uint4{pkx[0], pky[0], pkx[1], pky[1]};
        Bg1.u4 = uint4{pkx[2], pky[2], pkx[3], pky[3]};

        // ---- layer 3 (A3' = -2*W3 consumes r2; bias' via C-init) ----
        f32x4 c3 = MFMA16(A3[0], Bg0.v, Ci3);
        c3 = MFMA16(A3[1], Bg1.v, c3);

        if (g == 0) {
            const int pxg = pbase + it * 16;
            out[0 * NPIX + pxg] = c3[0];
            out[1 * NPIX + pxg] = c3[1];
            out[2 * NPIX + pxg] = c3[2];
            vmin = fminf(vmin, fminf(fminf(c3[0], c3[1]), c3[2]));
            vmax = fmaxf(vmax, fmaxf(fmaxf(c3[0], c3[1]), c3[2]));
        }
        cur = nxt;
    }

    // per-block min/max -> partials (no global atomics)
    #pragma unroll
    for (int off = 32; off > 0; off >>= 1) {
        vmin = fminf(vmin, __shfl_down(vmin, off));
        vmax = fmaxf(vmax, __shfl_down(vmax, off));
    }
    if (l == 0) { rmin[w] = vmin; rmax[w] = vmax; }
    __syncthreads();
    if (t == 0) {
        pmin[blockIdx.x] = fminf(fminf(rmin[0], rmin[1]), fminf(rmin[2], rmin[3]));
        pmax[blockIdx.x] = fmaxf(fmaxf(rmax[0], rmax[1]), fmaxf(rmax[2], rmax[3]));
    }
}

// fused reduce+norm: each block redundantly folds the 2048 partials (L2-hit),
// then normalizes its own float4 slice. Exact (min/max order-independent).
__global__ __launch_bounds__(256) void cppn_normred(
    float4* __restrict__ out,
    const float* __restrict__ pmin, const float* __restrict__ pmax)
{
    __shared__ float rmin[4], rmax[4];
    const int t = threadIdx.x, w = t >> 6, l = t & 63;
    float mn = INFINITY, mx = -INFINITY;
    #pragma unroll
    for (int i = 0; i < NBLK / 256; ++i) {
        mn = fminf(mn, pmin[i * 256 + t]);
        mx = fmaxf(mx, pmax[i * 256 + t]);
    }
    #pragma unroll
    for (int off = 32; off > 0; off >>= 1) {
        mn = fminf(mn, __shfl_down(mn, off));
        mx = fmaxf(mx, __shfl_down(mx, off));
    }
    if (l == 0) { rmin[w] = mn; rmax[w] = mx; }
    __syncthreads();
    mn = fminf(fminf(rmin[0], rmin[1]), fminf(rmin[2], rmin[3]));
    mx = fmaxf(fmaxf(rmax[0], rmax[1]), fmaxf(rmax[2], rmax[3]));
    const float inv = __fdividef(1.0f, mx - mn);

    const int i = blockIdx.x * 256 + t;
    float4 v = out[i];
    v.x = fminf(fmaxf((v.x - mn) * inv, 0.0f), 1.0f);
    v.y = fminf(fmaxf((v.y - mn) * inv, 0.0f), 1.0f);
    v.z = fminf(fmaxf((v.z - mn) * inv, 0.0f), 1.0f);
    v.w = fminf(fmaxf((v.w - mn) * inv, 0.0f), 1.0f);
    out[i] = v;
}

extern "C" void kernel_launch(void* const* d_in, const int* in_sizes, int n_in,
                              void* d_out, int out_size, void* d_ws, size_t ws_size,
                              hipStream_t stream) {
    const float* x  = (const float*)d_in[0];
    const float* W1 = (const float*)d_in[1];
    const float* b1 = (const float*)d_in[2];
    const float* W2 = (const float*)d_in[3];
    const float* b2 = (const float*)d_in[4];
    const float* W3 = (const float*)d_in[5];
    const float* b3 = (const float*)d_in[6];
    float* out = (float*)d_out;

    float* pmin = (float*)((char*)d_ws + 1024);          // 2048 floats
    float* pmax = (float*)((char*)d_ws + 1024 + 8192);   // 2048 floats

    cppn_main<<<NBLK, 256, 0, stream>>>(x, W1, b1, W2, b2, W3, b3, out, pmin, pmax);
    cppn_normred<<<NOUT4 / 256, 256, 0, stream>>>((float4*)out, pmin, pmax);
}

// Round 16
// 51.468 us; speedup vs baseline: 1.2910x; 1.2910x over previous
//
#include <hip/hip_runtime.h>
#include <math.h>

#define NPIX 1048576
#define HH 64
#define NO 3
#define NBLK 2048
#define ITER 8     // NBLK * 4 waves * ITER * 16 px = 1048576
#define NOUT4 786432             // NPIX*NO/4 float4s
#define K2C 2.8853900817779268f  // 2*log2(e)
#define NFRAG 18                 // per-lane uint4 fragments in fr

typedef float f32x4 __attribute__((ext_vector_type(4)));
typedef __bf16 bf16x8 __attribute__((ext_vector_type(8)));
typedef __bf16 bf16x2 __attribute__((ext_vector_type(2)));

union BF8 { __bf16 h[8]; bf16x8 v; uint4 u4; };
union PK2 { bf16x2 h; unsigned u; };
union F4U { float f[4]; uint4 u; f32x4 v; };

#define MFMA16(a, b, c) __builtin_amdgcn_mfma_f32_16x16x32_bf16((a), (b), (c), 0, 0, 0)

// k-slot -> physical h index permutation: lane (G,q) holds C rows {16m+4G+r}
// and owns B-frag k-slots {8G+j} (Bf0) and {32+8G+j} (Bf1). Bijection:
__device__ __forceinline__ int hsel(int k) {
    const int G = (k & 31) >> 3, j = k & 7;
    return ((k >= 32) ? 32 : 0) + ((j >= 4) ? 16 : 0) + 4 * G + (j & 3);
}

// sigmoid-reciprocal pack (R11 formulation — minimum issue count):
// r = 1/(exp2(t)+1), t pre-scaled by 2*log2e with bias folded upstream.
// tanh(x) = 1 - 2r is ABSORBED INTO THE NEXT LAYER: W' = -2W, bias' = bias + W.1.
// 6 VALU + 8 trans per 4 values. Overflow-safe: exp2->inf => rcp->0 => h=1.
__device__ __forceinline__ void rcp4_pack(const f32x4 c, unsigned* lo, unsigned* hi) {
    const float r0 = __builtin_amdgcn_rcpf(__builtin_amdgcn_exp2f(c[0]) + 1.0f);
    const float r1 = __builtin_amdgcn_rcpf(__builtin_amdgcn_exp2f(c[1]) + 1.0f);
    const float r2 = __builtin_amdgcn_rcpf(__builtin_amdgcn_exp2f(c[2]) + 1.0f);
    const float r3 = __builtin_amdgcn_rcpf(__builtin_amdgcn_exp2f(c[3]) + 1.0f);
    PK2 L, H;
    L.h = bf16x2{(__bf16)r0, (__bf16)r1};
    H.h = bf16x2{(__bf16)r2, (__bf16)r3};
    *lo = L.u; *hi = H.u;
}

// ---- pre-pack, 4-wave parallel (layout per lane: 18 uint4 + 1 shared) ----
// [0..3]=A1 (K2-scaled, bias k-aug), [4..11]=A2' = -2*K2*W2 (k-permuted),
// [12..13]=A3' = -2*W3 (k-permuted), [14..17]=Ci2' = K2*(b2 + colsum(W2)).
// fr[NFRAG*64] = b3' = b3 + colsum(W3).
__global__ __launch_bounds__(256) void cppn_pack(
    const float* __restrict__ W1, const float* __restrict__ b1,
    const float* __restrict__ W2, const float* __restrict__ b2,
    const float* __restrict__ W3, const float* __restrict__ b3,
    uint4* __restrict__ fr)
{
    __shared__ float cs2p[4][HH];  // partial column sums of W2
    __shared__ float cs3p[4][NO];  // partial column sums of W3
    const int t = threadIdx.x, w = t >> 6, l = t & 63, g = l >> 4, q = l & 15;

    // cooperative column sums: thread t sums 16 rows of column (t&63)
    {
        const int col = t & 63, part = t >> 6;
        float s = 0.0f;
        #pragma unroll
        for (int r = 0; r < 16; ++r) s += W2[(part * 16 + r) * HH + col];
        cs2p[part][col] = s;
    }
    if (t < 12) {
        const int o = t % 3, part = t / 3;
        float s = 0.0f;
        #pragma unroll
        for (int r = 0; r < 16; ++r) s += W3[(part * 16 + r) * NO + o];
        cs3p[part][o] = s;
    }
    __syncthreads();

    uint4* o = fr + l * NFRAG;

    if (w == 0) {
        // L1: A[row=h][k] = K2 * W1aug[k][h]; k<4 -> W1, k==4 -> b1 (bias fold)
        #pragma unroll
        for (int m = 0; m < 4; ++m) {
            BF8 tt;
            #pragma unroll
            for (int j = 0; j < 8; ++j) {
                const int k = g * 8 + j;
                float v = 0.0f;
                if (k < 4) v = W1[k * HH + m * 16 + q];
                else if (k == 4) v = b1[m * 16 + q];
                tt.h[j] = (__bf16)(K2C * v);
            }
            o[m] = tt.u4;
        }
    } else if (w == 1 || w == 2) {
        // L2: A'[row=h2][k] = -2*K2 * W2[hsel(k)][h2]  (consumes r1, not h1)
        const int s = w - 1;
        #pragma unroll
        for (int m = 0; m < 4; ++m) {
            BF8 tt;
            #pragma unroll
            for (int j = 0; j < 8; ++j)
                tt.h[j] = (__bf16)(-2.0f * K2C * W2[hsel(s * 32 + g * 8 + j) * HH + m * 16 + q]);
            o[4 + s * 4 + m] = tt.u4;
        }
    } else {
        // L3: A'[row=o][k] = -2 * W3[hsel(k)][o], rows 3..15 zero
        #pragma unroll
        for (int s = 0; s < 2; ++s) {
            BF8 tt;
            #pragma unroll
            for (int j = 0; j < 8; ++j)
                tt.h[j] = (q < NO) ? (__bf16)(-2.0f * W3[hsel(s * 32 + g * 8 + j) * NO + q])
                                   : (__bf16)0.0f;
            o[12 + s] = tt.u4;
        }
        // Ci2' = K2 * (b2 + colsum(W2)) at C rows m*16 + g*4 + r
        #pragma unroll
        for (int m = 0; m < 4; ++m) {
            F4U tt;
            #pragma unroll
            for (int r = 0; r < 4; ++r) {
                const int idx = m * 16 + g * 4 + r;
                const float cs = cs2p[0][idx] + cs2p[1][idx] + cs2p[2][idx] + cs2p[3][idx];
                tt.f[r] = K2C * (b2[idx] + cs);
            }
            o[14 + m] = tt.u;
        }
        // b3' = b3 + colsum(W3), one shared uint4 slot
        if (l == 0) {
            F4U tt;
            #pragma unroll
            for (int c = 0; c < 3; ++c)
                tt.f[c] = b3[c] + cs3p[0][c] + cs3p[1][c] + cs3p[2][c] + cs3p[3][c];
            tt.f[3] = 0.0f;
            fr[NFRAG * 64] = tt.u;
        }
    }
}

__global__ __launch_bounds__(256) void cppn_main(
    const float* __restrict__ x,
    const uint4* __restrict__ fr,
    float* __restrict__ out,
    float* __restrict__ pmin, float* __restrict__ pmax)
{
    __shared__ float rmin[4], rmax[4];

    const int t = threadIdx.x;
    const int w = t >> 6;
    const int l = t & 63;
    const int g = l >> 4;
    const int q = l & 15;

    // ---- load prebuilt fragments (19 dwordx4, L2-hit) ----
    const uint4* fo = fr + l * NFRAG;
    bf16x8 A1[4], A2[2][4], A3[2];
    #pragma unroll
    for (int m = 0; m < 4; ++m) { BF8 u; u.u4 = fo[m]; A1[m] = u.v; }
    #pragma unroll
    for (int s = 0; s < 2; ++s)
        #pragma unroll
        for (int m = 0; m < 4; ++m) { BF8 u; u.u4 = fo[4 + s * 4 + m]; A2[s][m] = u.v; }
    #pragma unroll
    for (int s = 0; s < 2; ++s) { BF8 u; u.u4 = fo[12 + s]; A3[s] = u.v; }
    f32x4 Ci2[4];
    #pragma unroll
    for (int m = 0; m < 4; ++m) { F4U u; u.u = fo[14 + m]; Ci2[m] = u.v; }
    // b3' folded into L3 C-init: lane (g,q) holds C rows 4g+r -> rows 0..2 live on g==0
    F4U b3u; b3u.u = fr[NFRAG * 64];
    f32x4 Ci3 = {0.0f, 0.0f, 0.0f, 0.0f};
    if (g == 0) { Ci3[0] = b3u.f[0]; Ci3[1] = b3u.f[1]; Ci3[2] = b3u.f[2]; }

    const f32x4 z = {0.0f, 0.0f, 0.0f, 0.0f};
    float vmin = INFINITY, vmax = -INFINITY;

    const int pbase = ((blockIdx.x * 4 + w) * ITER) * 16 + q;  // pixel index, it steps +16
    const float4* x4 = reinterpret_cast<const float4*>(x);
    float4 cur = x4[pbase];

    #pragma unroll 2
    for (int it = 0; it < ITER; ++it) {
        // prefetch next iteration's x before the long compute body
        const int itn = (it + 1 < ITER) ? it + 1 : it;
        const float4 nxt = x4[pbase + itn * 16];

        // B1 frag: xaug^T[k][px]; only g==0 lanes carry {x0..x3, 1}
        BF8 bx;
        bx.u4 = uint4{0, 0, 0, 0};
        if (g == 0) {
            PK2 p01, p23;
            p01.h = bf16x2{(__bf16)cur.x, (__bf16)cur.y};
            p23.h = bf16x2{(__bf16)cur.z, (__bf16)cur.w};
            bx.u4.x = p01.u;
            bx.u4.y = p23.u;
            bx.u4.z = 0x3F80u;  // {1.0bf16, 0} bias lane k=4
        }

        // ---- layer 1 (A1 pre-scaled by K2, bias k-augmented) ----
        f32x4 c1[4];
        #pragma unroll
        for (int m = 0; m < 4; ++m) c1[m] = MFMA16(A1[m], bx.v, z);

        unsigned pkx[4], pky[4];
        #pragma unroll
        for (int m = 0; m < 4; ++m) rcp4_pack(c1[m], &pkx[m], &pky[m]);
        BF8 Bf0, Bf1;
        Bf0.u4 = uint4{pkx[0], pky[0], pkx[1], pky[1]};
        Bf1.u4 = uint4{pkx[2], pky[2], pkx[3], pky[3]};

        // ---- layer 2 (A2' = -2*K2*W2 consumes r1; bias' via C-init) ----
        f32x4 c2[4];
        #pragma unroll
        for (int m = 0; m < 4; ++m) {
            c2[m] = MFMA16(A2[0][m], Bf0.v, Ci2[m]);
            c2[m] = MFMA16(A2[1][m], Bf1.v, c2[m]);
        }
        #pragma unroll
        for (int m = 0; m < 4; ++m) rcp4_pack(c2[m], &pkx[m], &pky[m]);
        BF8 Bg0, Bg1;
        Bg0.u4 = uint4{pkx[0], pky[0], pkx[1], pky[1]};
        Bg1.u4 = uint4{pkx[2], pky[2], pkx[3], pky[3]};

        // ---- layer 3 (A3' = -2*W3 consumes r2; bias' via C-init) ----
        f32x4 c3 = MFMA16(A3[0], Bg0.v, Ci3);
        c3 = MFMA16(A3[1], Bg1.v, c3);

        if (g == 0) {
            const int pxg = pbase + it * 16;
            out[0 * NPIX + pxg] = c3[0];
            out[1 * NPIX + pxg] = c3[1];
            out[2 * NPIX + pxg] = c3[2];
            vmin = fminf(vmin, fminf(fminf(c3[0], c3[1]), c3[2]));
            vmax = fmaxf(vmax, fmaxf(fmaxf(c3[0], c3[1]), c3[2]));
        }
        cur = nxt;
    }

    // per-block min/max -> partials (no global atomics)
    #pragma unroll
    for (int off = 32; off > 0; off >>= 1) {
        vmin = fminf(vmin, __shfl_down(vmin, off));
        vmax = fmaxf(vmax, __shfl_down(vmax, off));
    }
    if (l == 0) { rmin[w] = vmin; rmax[w] = vmax; }
    __syncthreads();
    if (t == 0) {
        pmin[blockIdx.x] = fminf(fminf(rmin[0], rmin[1]), fminf(rmin[2], rmin[3]));
        pmax[blockIdx.x] = fmaxf(fmaxf(rmax[0], rmax[1]), fmaxf(rmax[2], rmax[3]));
    }
}

// fused reduce+norm: each block redundantly folds the 2048 partials (L2-hit),
// then normalizes its own float4 slice. Exact (min/max order-independent).
__global__ __launch_bounds__(256) void cppn_normred(
    float4* __restrict__ out,
    const float* __restrict__ pmin, const float* __restrict__ pmax)
{
    __shared__ float rmin[4], rmax[4];
    const int t = threadIdx.x, w = t >> 6, l = t & 63;
    float mn = INFINITY, mx = -INFINITY;
    #pragma unroll
    for (int i = 0; i < NBLK / 256; ++i) {
        mn = fminf(mn, pmin[i * 256 + t]);
        mx = fmaxf(mx, pmax[i * 256 + t]);
    }
    #pragma unroll
    for (int off = 32; off > 0; off >>= 1) {
        mn = fminf(mn, __shfl_down(mn, off));
        mx = fmaxf(mx, __shfl_down(mx, off));
    }
    if (l == 0) { rmin[w] = mn; rmax[w] = mx; }
    __syncthreads();
    mn = fminf(fminf(rmin[0], rmin[1]), fminf(rmin[2], rmin[3]));
    mx = fmaxf(fmaxf(rmax[0], rmax[1]), fmaxf(rmax[2], rmax[3]));
    const float inv = __fdividef(1.0f, mx - mn);

    const int i = blockIdx.x * 256 + t;
    float4 v = out[i];
    v.x = fminf(fmaxf((v.x - mn) * inv, 0.0f), 1.0f);
    v.y = fminf(fmaxf((v.y - mn) * inv, 0.0f), 1.0f);
    v.z = fminf(fmaxf((v.z - mn) * inv, 0.0f), 1.0f);
    v.w = fminf(fmaxf((v.w - mn) * inv, 0.0f), 1.0f);
    out[i] = v;
}

extern "C" void kernel_launch(void* const* d_in, const int* in_sizes, int n_in,
                              void* d_out, int out_size, void* d_ws, size_t ws_size,
                              hipStream_t stream) {
    const float* x  = (const float*)d_in[0];
    const float* W1 = (const float*)d_in[1];
    const float* b1 = (const float*)d_in[2];
    const float* W2 = (const float*)d_in[3];
    const float* b2 = (const float*)d_in[4];
    const float* W3 = (const float*)d_in[5];
    const float* b3 = (const float*)d_in[6];
    float* out = (float*)d_out;

    float* pmin = (float*)((char*)d_ws + 1024);          // 2048 floats
    float* pmax = (float*)((char*)d_ws + 1024 + 8192);   // 2048 floats
    uint4* fr   = (uint4*)((char*)d_ws + 32768);         // 64*18+1 uint4 ≈ 18 KB

    cppn_pack<<<1, 256, 0, stream>>>(W1, b1, W2, b2, W3, b3, fr);
    cppn_main<<<NBLK, 256, 0, stream>>>(x, fr, out, pmin, pmax);
    cppn_normred<<<NOUT4 / 256, 256, 0, stream>>>((float4*)out, pmin, pmax);
}